// Round 1
// baseline (25.706 us; speedup 1.0000x reference)
//
#include <hip/hip_runtime.h>
#include <math.h>

#define NPTS 2048
#define KDIM 400

// ---------------- Kernel 1: FF network (blocks 0..63) + sparse kval (blocks 64..191)
__global__ __launch_bounds__(256) void k_ff_and_kval(
    const float* __restrict__ weights, const float* __restrict__ grid,
    const float* __restrict__ ff_w1, const float* __restrict__ ff_b1,
    const float* __restrict__ ff_w2, const float* __restrict__ ff_b2,
    const float* __restrict__ ff_w3, const float* __restrict__ ff_b3,
    const float* __restrict__ k_w1, const float* __restrict__ k_b1,
    const float* __restrict__ k_w2, const float* __restrict__ k_b2,
    const float* __restrict__ k_w3, const float* __restrict__ k_b3,
    float* __restrict__ integ, float* __restrict__ kv0,
    float* __restrict__ kv1, int* __restrict__ kidx)
{
    const int t = threadIdx.x;
    if (blockIdx.x < 64) {
        // ---- FeedForward: one batch row per block ----
        const int b = blockIdx.x;
        __shared__ float wrow[256];
        __shared__ float h1[120];
        __shared__ float h2[240];
        wrow[t] = weights[b * 256 + t];
        __syncthreads();
        if (t < 120) {
            float s = ff_b1[t];
            #pragma unroll 8
            for (int i = 0; i < 256; ++i) s = fmaf(wrow[i], ff_w1[i * 120 + t], s);
            h1[t] = tanhf(s);
        }
        __syncthreads();
        if (t < 240) {
            float s = ff_b2[t];
            #pragma unroll 8
            for (int i = 0; i < 120; ++i) s = fmaf(h1[i], ff_w2[i * 240 + t], s);
            h2[t] = tanhf(s);
        }
        __syncthreads();
        for (int o = t; o < 400; o += 256) {
            float s = ff_b3[o];
            #pragma unroll 8
            for (int i = 0; i < 240; ++i) s = fmaf(h2[i], ff_w3[i * 400 + o], s);
            integ[b * 400 + o] = s;
        }
    } else {
        // ---- sparse kernel-MLP eval: one thread per (n, window-slot) ----
        __shared__ float sw1[80], sb1[40], sw2[800], sb2[40], sw3[40], sb3[2];
        for (int i = t; i < 80;  i += 256) sw1[i] = k_w1[i];
        for (int i = t; i < 800; i += 256) sw2[i] = k_w2[i];
        if (t < 40) { sb1[t] = k_b1[t]; sb2[t] = k_b2[t]; sw3[t] = k_w3[t]; }
        if (t < 2)  sb3[t] = k_b3[t];
        __syncthreads();

        const int pid  = blockIdx.x - 64;       // 0..127, 16 points each
        const int n    = pid * 16 + (t & 15);
        const int slot = t >> 4;                // 0..15 -> (dx,dy) in 4x4 window
        const float x = grid[n * 2 + 0];
        const float y = grid[n * 2 + 1];
        // candidate window base: all active i satisfy ilo <= i <= ilo+3
        // (0.01 slack >> f32 rounding; exact membership re-tested below)
        const int ilx = (int)ceilf((x - 0.15f) * 20.0f - 0.01f);
        const int ily = (int)ceilf((y - 0.15f) * 20.0f - 0.01f);
        const int ix = ilx + (slot >> 2);
        const int iy = ily + (slot & 3);

        float kva = 0.f, kvb = 0.f;
        int k = 0;
        if (ix >= 0 && ix < 20 && iy >= 0 && iy < 20) {
            // replicate reference f32 arithmetic exactly (no fp-contract)
            const float gx = __fmul_rn((float)ix, 0.05f);
            const float gy = __fmul_rn((float)iy, 0.05f);
            const float lx = __fsub_rn(x, gx);
            const float ly = __fsub_rn(y, gy);
            if (lx >= 0.f && lx <= 0.15f && ly >= 0.f && ly <= 0.15f) {
                k = ix * 20 + iy;
                #pragma unroll
                for (int f = 0; f < 2; ++f) {
                    float hv[20];
                    #pragma unroll
                    for (int hh = 0; hh < 20; ++hh)
                        hv[hh] = fmaxf(0.f,
                            fmaf(lx, sw1[f * 40 + hh],
                            fmaf(ly, sw1[f * 40 + 20 + hh], sb1[f * 20 + hh])));
                    float o = sb3[f];
                    #pragma unroll
                    for (int g = 0; g < 20; ++g) {
                        float s = sb2[f * 20 + g];
                        #pragma unroll
                        for (int hh = 0; hh < 20; ++hh)
                            s = fmaf(hv[hh], sw2[f * 400 + hh * 20 + g], s);
                        o = fmaf(fmaxf(0.f, s), sw3[f * 20 + g], o);
                    }
                    if (f == 0) kva = o; else kvb = o;
                }
            }
        }
        // [16][2048] layout -> kernel 2 reads coalesced over n
        kv0 [slot * NPTS + n] = kva;
        kv1 [slot * NPTS + n] = kvb;
        kidx[slot * NPTS + n] = k;   // k=0 with kv=0 contributes nothing
    }
}

// ---------------- Kernel 2: fields[b,n,f] = sigmoid(sum_j kv[f,n,j] * integ[b, kidx[n,j]])
__global__ __launch_bounds__(256) void k_field(
    const float* __restrict__ integ, const float* __restrict__ kv0,
    const float* __restrict__ kv1, const int* __restrict__ kidx,
    float2* __restrict__ out)
{
    const int tid = blockIdx.x * 256 + threadIdx.x;   // 64*2048 threads
    const int b = tid >> 11;
    const int n = tid & (NPTS - 1);
    const float* __restrict__ irow = integ + b * KDIM;
    float a0 = 0.f, a1 = 0.f;
    #pragma unroll
    for (int j = 0; j < 16; ++j) {
        const int k = kidx[j * NPTS + n];
        const float w = irow[k];
        a0 = fmaf(kv0[j * NPTS + n], w, a0);
        a1 = fmaf(kv1[j * NPTS + n], w, a1);
    }
    out[tid] = make_float2(1.f / (1.f + expf(-a0)),
                           1.f / (1.f + expf(-a1)));
}

extern "C" void kernel_launch(void* const* d_in, const int* in_sizes, int n_in,
                              void* d_out, int out_size, void* d_ws, size_t ws_size,
                              hipStream_t stream) {
    const float* weights = (const float*)d_in[0];
    const float* grid    = (const float*)d_in[1];
    const float* ff_w1   = (const float*)d_in[2];
    const float* ff_b1   = (const float*)d_in[3];
    const float* ff_w2   = (const float*)d_in[4];
    const float* ff_b2   = (const float*)d_in[5];
    const float* ff_w3   = (const float*)d_in[6];
    const float* ff_b3   = (const float*)d_in[7];
    const float* k_w1    = (const float*)d_in[8];
    const float* k_b1    = (const float*)d_in[9];
    const float* k_w2    = (const float*)d_in[10];
    const float* k_b2    = (const float*)d_in[11];
    const float* k_w3    = (const float*)d_in[12];
    const float* k_b3    = (const float*)d_in[13];

    float* integ = (float*)d_ws;                 // 64*400
    float* kv0   = integ + 64 * KDIM;            // 16*2048
    float* kv1   = kv0 + 16 * NPTS;              // 16*2048
    int*   kidx  = (int*)(kv1 + 16 * NPTS);      // 16*2048

    k_ff_and_kval<<<64 + 128, 256, 0, stream>>>(
        weights, grid, ff_w1, ff_b1, ff_w2, ff_b2, ff_w3, ff_b3,
        k_w1, k_b1, k_w2, k_b2, k_w3, k_b3,
        integ, kv0, kv1, kidx);

    k_field<<<(64 * NPTS) / 256, 256, 0, stream>>>(
        integ, kv0, kv1, kidx, (float2*)d_out);
}

// Round 2
// 15.711 us; speedup vs baseline: 1.6361x; 1.6361x over previous
//
#include <hip/hip_runtime.h>
#include <math.h>

#define NPTS 2048
#define KDIM 400

// Kernel 1: blocks 0..127 = FF net (2 blocks per batch row, split-K layers)
//           blocks 128..191 = sparse kernel-MLP eval (32 points x 16 slots each)
__global__ __launch_bounds__(512) void k_ff_and_kval(
    const float* __restrict__ weights, const float* __restrict__ grid,
    const float* __restrict__ ff_w1, const float* __restrict__ ff_b1,
    const float* __restrict__ ff_w2, const float* __restrict__ ff_b2,
    const float* __restrict__ ff_w3, const float* __restrict__ ff_b3,
    const float* __restrict__ k_w1, const float* __restrict__ k_b1,
    const float* __restrict__ k_w2, const float* __restrict__ k_b2,
    const float* __restrict__ k_w3, const float* __restrict__ k_b3,
    float* __restrict__ integ, float* __restrict__ kv0,
    float* __restrict__ kv1, int* __restrict__ kidx)
{
    const int t = threadIdx.x;
    if (blockIdx.x < 128) {
        // ---- FeedForward: block pair (b, half) ----
        const int b    = blockIdx.x >> 1;
        const int half = blockIdx.x & 1;
        __shared__ float wrow[256];
        __shared__ float h1[120];
        __shared__ float h2[240];
        __shared__ float p1[4][120];
        __shared__ float p2[2][240];
        __shared__ float p3[2][200];

        if (t < 256) wrow[t] = weights[b * 256 + t];
        __syncthreads();

        // layer 1: 120 outputs, 4-way split-K over 256 inputs (64 each)
        if (t < 480) {
            const int seg = t / 120;
            const int o   = t - seg * 120;
            float s = (seg == 0) ? ff_b1[o] : 0.f;
            const int i0 = seg * 64;
            #pragma unroll 16
            for (int i = 0; i < 64; ++i)
                s = fmaf(wrow[i0 + i], ff_w1[(i0 + i) * 120 + o], s);
            p1[seg][o] = s;
        }
        __syncthreads();
        if (t < 120) h1[t] = tanhf(p1[0][t] + p1[1][t] + p1[2][t] + p1[3][t]);
        __syncthreads();

        // layer 2: 240 outputs, 2-way split-K over 120 inputs (60 each)
        if (t < 480) {
            const int seg = t / 240;
            const int o   = t - seg * 240;
            float s = (seg == 0) ? ff_b2[o] : 0.f;
            const int i0 = seg * 60;
            #pragma unroll 15
            for (int i = 0; i < 60; ++i)
                s = fmaf(h1[i0 + i], ff_w2[(i0 + i) * 240 + o], s);
            p2[seg][o] = s;
        }
        __syncthreads();
        if (t < 240) h2[t] = tanhf(p2[0][t] + p2[1][t]);
        __syncthreads();

        // layer 3: this block's 200 outputs, 2-way split-K over 240 inputs
        if (t < 400) {
            const int seg = t / 200;
            const int o   = t - seg * 200;
            const int oc  = half * 200 + o;          // global output column
            float s = (seg == 0) ? ff_b3[oc] : 0.f;
            const int i0 = seg * 120;
            #pragma unroll 15
            for (int i = 0; i < 120; ++i)
                s = fmaf(h2[i0 + i], ff_w3[(i0 + i) * 400 + oc], s);
            p3[seg][o] = s;
        }
        __syncthreads();
        if (t < 200) integ[b * 400 + half * 200 + t] = p3[0][t] + p3[1][t];
    } else {
        // ---- sparse kernel-MLP eval: one thread per (n, window-slot) ----
        __shared__ float sw1[80], sb1[40], sw2[800], sb2[40], sw3[40], sb3[2];
        for (int i = t; i < 80;  i += 512) sw1[i] = k_w1[i];
        for (int i = t; i < 800; i += 512) sw2[i] = k_w2[i];
        if (t < 40) { sb1[t] = k_b1[t]; sb2[t] = k_b2[t]; sw3[t] = k_w3[t]; }
        if (t < 2)  sb3[t] = k_b3[t];
        __syncthreads();

        const int pid  = blockIdx.x - 128;      // 0..63, 32 points each
        const int n    = pid * 32 + (t & 31);
        const int slot = t >> 5;                // 0..15 -> (dx,dy) in 4x4 window
        const float2 g2 = ((const float2*)grid)[n];
        const float x = g2.x, y = g2.y;
        // candidate window base: all active i satisfy ilo <= i <= ilo+3
        const int ilx = (int)ceilf((x - 0.15f) * 20.0f - 0.01f);
        const int ily = (int)ceilf((y - 0.15f) * 20.0f - 0.01f);
        const int ix = ilx + (slot >> 2);
        const int iy = ily + (slot & 3);

        float kva = 0.f, kvb = 0.f;
        int k = 0;
        if (ix >= 0 && ix < 20 && iy >= 0 && iy < 20) {
            // replicate reference f32 arithmetic exactly (no fp-contract)
            const float gx = __fmul_rn((float)ix, 0.05f);
            const float gy = __fmul_rn((float)iy, 0.05f);
            const float lx = __fsub_rn(x, gx);
            const float ly = __fsub_rn(y, gy);
            if (lx >= 0.f && lx <= 0.15f && ly >= 0.f && ly <= 0.15f) {
                k = ix * 20 + iy;
                #pragma unroll
                for (int f = 0; f < 2; ++f) {
                    float hv[20];
                    #pragma unroll
                    for (int hh = 0; hh < 20; ++hh)
                        hv[hh] = fmaxf(0.f,
                            fmaf(lx, sw1[f * 40 + hh],
                            fmaf(ly, sw1[f * 40 + 20 + hh], sb1[f * 20 + hh])));
                    float o = sb3[f];
                    #pragma unroll
                    for (int g = 0; g < 20; ++g) {
                        float s = sb2[f * 20 + g];
                        #pragma unroll
                        for (int hh = 0; hh < 20; ++hh)
                            s = fmaf(hv[hh], sw2[f * 400 + hh * 20 + g], s);
                        o = fmaf(fmaxf(0.f, s), sw3[f * 20 + g], o);
                    }
                    if (f == 0) kva = o; else kvb = o;
                }
            }
        }
        // [16][2048] layout -> kernel 2 reads coalesced over n
        kv0 [slot * NPTS + n] = kva;
        kv1 [slot * NPTS + n] = kvb;
        kidx[slot * NPTS + n] = k;   // k=0 with kv=0 contributes nothing
    }
}

// Kernel 2: fields[b,n,f] = sigmoid(sum_j kv[f,n,j] * integ[b, kidx[n,j]])
__global__ __launch_bounds__(256) void k_field(
    const float* __restrict__ integ, const float* __restrict__ kv0,
    const float* __restrict__ kv1, const int* __restrict__ kidx,
    float2* __restrict__ out)
{
    const int tid = blockIdx.x * 256 + threadIdx.x;   // 64*2048 threads
    const int b = tid >> 11;
    const int n = tid & (NPTS - 1);
    const float* __restrict__ irow = integ + b * KDIM;
    float a0 = 0.f, a1 = 0.f;
    #pragma unroll
    for (int j = 0; j < 16; ++j) {
        const int k = kidx[j * NPTS + n];
        const float w = irow[k];
        a0 = fmaf(kv0[j * NPTS + n], w, a0);
        a1 = fmaf(kv1[j * NPTS + n], w, a1);
    }
    out[tid] = make_float2(1.f / (1.f + __expf(-a0)),
                           1.f / (1.f + __expf(-a1)));
}

extern "C" void kernel_launch(void* const* d_in, const int* in_sizes, int n_in,
                              void* d_out, int out_size, void* d_ws, size_t ws_size,
                              hipStream_t stream) {
    const float* weights = (const float*)d_in[0];
    const float* grid    = (const float*)d_in[1];
    const float* ff_w1   = (const float*)d_in[2];
    const float* ff_b1   = (const float*)d_in[3];
    const float* ff_w2   = (const float*)d_in[4];
    const float* ff_b2   = (const float*)d_in[5];
    const float* ff_w3   = (const float*)d_in[6];
    const float* ff_b3   = (const float*)d_in[7];
    const float* k_w1    = (const float*)d_in[8];
    const float* k_b1    = (const float*)d_in[9];
    const float* k_w2    = (const float*)d_in[10];
    const float* k_b2    = (const float*)d_in[11];
    const float* k_w3    = (const float*)d_in[12];
    const float* k_b3    = (const float*)d_in[13];

    float* integ = (float*)d_ws;                 // 64*400
    float* kv0   = integ + 64 * KDIM;            // 16*2048
    float* kv1   = kv0 + 16 * NPTS;              // 16*2048
    int*   kidx  = (int*)(kv1 + 16 * NPTS);      // 16*2048

    k_ff_and_kval<<<128 + 64, 512, 0, stream>>>(
        weights, grid, ff_w1, ff_b1, ff_w2, ff_b2, ff_w3, ff_b3,
        k_w1, k_b1, k_w2, k_b2, k_w3, k_b3,
        integ, kv0, kv1, kidx);

    k_field<<<(64 * NPTS) / 256, 256, 0, stream>>>(
        integ, kv0, kv1, kidx, (float2*)d_out);
}